// Round 1
// 321.725 us; speedup vs baseline: 1.0916x; 1.0916x over previous
//
#include <hip/hip_runtime.h>
#include <stdint.h>

typedef int v4i   __attribute__((ext_vector_type(4)));
typedef int v16i  __attribute__((ext_vector_type(16)));

#define B_    128
#define C_    64
#define H_    56
#define W_    56
#define HW_   3136
#define NELEM (B_*C_*HW_)          // 25,690,112

// workspace layout (bytes)
#define OFF_K0   0                                  // int8 [B][H][W][C] quantized x (NHWC)
#define OFF_K1   ((size_t)NELEM)                    // int8 x1 (NHWC)
#define OFF_WB   ((size_t)2*NELEM)                  // int8 [2][4][9][64][16] (layer, ci-chunk, tap, co, ci-low) signs
#define OFF_PAR  (OFF_WB + 2*4*9*64*16)             // float: [0..127] qw, [128..255] qb, [256..383] scale=2^p/7
#define OFF_MAX  (OFF_PAR + 384*4)                  // uint32 absmax bits

// --------------------------- numpy-pairwise-faithful wave reduction (576-elem)
__device__ __forceinline__ float pw_reduce64(float r) {
    r = __fadd_rn(r, __shfl_xor(r, 1, 64));
    r = __fadd_rn(r, __shfl_xor(r, 2, 64));
    r = __fadd_rn(r, __shfl_xor(r, 4, 64));
    r = __fadd_rn(r, __shfl_xor(r, 8, 64));
    r = __fadd_rn(r, __shfl_xor(r, 16, 64));
    r = __fadd_rn(r, __shfl_xor(r, 32, 64));
    return r;
}

// ---------------------------------------------------------------- fused prep
// blocks 0..1023   : absmax(x) -> maxbits (one atomic per block)
// blocks 1024..1055: weight binarization, 4 waves/block, wave = (layer, co)
// block  1056      : BN folded affine (threads 0..127)
__global__ void k_pre(const float* __restrict__ x, unsigned* __restrict__ maxbits,
                      const float* __restrict__ w1, const float* __restrict__ w2,
                      int8_t* __restrict__ wb, float* __restrict__ par,
                      const float* __restrict__ g1, const float* __restrict__ bb1,
                      const float* __restrict__ mm1, const float* __restrict__ vv1,
                      const float* __restrict__ g2, const float* __restrict__ bb2,
                      const float* __restrict__ mm2, const float* __restrict__ vv2) {
    __shared__ float smax[4];
    const int b = blockIdx.x;
    const int tid = threadIdx.x;
    if (b < 1024) {
        float m = 0.f;
        const int n4 = NELEM / 4;
        for (int i = b * 256 + tid; i < n4; i += 1024 * 256) {
            float4 v = ((const float4*)x)[i];
            m = fmaxf(m, fmaxf(fmaxf(fabsf(v.x), fabsf(v.y)), fmaxf(fabsf(v.z), fabsf(v.w))));
        }
        for (int off = 32; off; off >>= 1) m = fmaxf(m, __shfl_down(m, off, 64));
        if ((tid & 63) == 0) smax[tid >> 6] = m;
        __syncthreads();
        if (tid == 0) {
            float mm = fmaxf(fmaxf(smax[0], smax[1]), fmaxf(smax[2], smax[3]));
            atomicMax(maxbits, __float_as_uint(mm));   // nonneg floats: uint order == float order
        }
    } else if (b < 1056) {
        const int idx = (b - 1024) * 4 + (tid >> 6);
        const int layer = idx >> 6, co = idx & 63;
        const int lane = tid & 63;
        const float* w = (layer ? w2 : w1) + (size_t)co * 576;
        const int base = (lane >> 3) * 72 + (lane & 7);

        float v[9];
#pragma unroll
        for (int i = 0; i < 9; i++) v[i] = w[base + 8 * i];

        float s = v[0];
#pragma unroll
        for (int i = 1; i < 9; i++) s = __fadd_rn(s, v[i]);
        const float mean = __fdiv_rn(pw_reduce64(s), 576.0f);

        float d0 = __fsub_rn(v[0], mean);
        float sq = __fmul_rn(d0, d0);
#pragma unroll
        for (int i = 1; i < 9; i++) {
            float d = __fsub_rn(v[i], mean);
            sq = __fadd_rn(sq, __fmul_rn(d, d));
        }
        const float sig = __fsqrt_rn(__fdiv_rn(pw_reduce64(sq), 575.0f));

        float sa = fabsf(__fdiv_rn(__fsub_rn(v[0], mean), sig));
#pragma unroll
        for (int i = 1; i < 9; i++)
            sa = __fadd_rn(sa, fabsf(__fdiv_rn(__fsub_rn(v[i], mean), sig)));
        const float ma = __fdiv_rn(pw_reduce64(sa), 576.0f);
        const float p  = rintf(log2f(ma));
        if (lane == 0) par[256 + layer * 64 + co] = __fdiv_rn(exp2f(p), 7.0f);

        // signs -> wb[layer][ci>>4][tap][co][ci&15]  (conv-LDS order, staged linearly)
#pragma unroll
        for (int i = 0; i < 9; i++) {
            int ig = base + 8 * i;
            float d = __fsub_rn(v[i], mean);
            int8_t sg = (d > 0.0f) ? (int8_t)1 : ((d < 0.0f) ? (int8_t)-1 : (int8_t)0);
            int ci = ig / 9, tp = ig % 9;
            wb[((((size_t)layer * 4 + (ci >> 4)) * 9 + tp) * 64 + co) * 16 + (ci & 15)] = sg;
        }
    } else {
        if (tid < 128) {
            const int layer = tid >> 6;
            const int c = tid & 63;
            const float* g  = layer ? g2  : g1;
            const float* be = layer ? bb2 : bb1;
            const float* mu = layer ? mm2 : mm1;
            const float* va = layer ? vv2 : vv1;
            const float stdv = __fsqrt_rn(__fadd_rn(va[c], 1e-5f));
            const float w = __fdiv_rn(g[c], stdv);
            const float bb = __fsub_rn(be[c], __fmul_rn(w, mu[c]));
            float aw = fabsf(w), ab = fabsf(bb);
            for (int off = 32; off; off >>= 1) {
                aw = fmaxf(aw, __shfl_xor(aw, off, 64));
                ab = fmaxf(ab, __shfl_xor(ab, off, 64));
            }
            const float Tw = fminf(fmaxf(aw, 1e-10f), 255.0f);
            const float Tb = fminf(fmaxf(ab, 1e-10f), 255.0f);
            {   // quantize(w, 3): n = 7
                float vq = __fdiv_rn(fminf(fmaxf(w, -Tw), Tw), Tw);
                float r  = rintf(__fmul_rn(vq, 7.0f));
                float qf = __fadd_rn(vq, __fsub_rn(__fdiv_rn(r, 7.0f), vq));
                par[layer * 64 + c] = __fmul_rn(qf, Tw);
            }
            {   // quantize(b, 12): n = 4095
                float vq = __fdiv_rn(fminf(fmaxf(bb, -Tb), Tb), Tb);
                float r  = rintf(__fmul_rn(vq, 4095.0f));
                float qf = __fadd_rn(vq, __fsub_rn(__fdiv_rn(r, 4095.0f), vq));
                par[128 + layer * 64 + c] = __fmul_rn(qf, Tb);
            }
        }
    }
}

// ------------------------------------- quantize x -> int8 k in NHWC layout
// thread = (4-channel block, 4-x block); packs 4 channels per dword -> no byte
// LDS ops. Division by runtime T via correctly-rounded f64 reciprocal multiply
// (bit-identical to __fdiv_rn: f32 quotient is >= 2^-48 rel. from any rounding
// boundary, f64 path error <= 1.5*2^-52).
__global__ void k_quant(const float* __restrict__ x, const unsigned* __restrict__ maxbits,
                        int8_t* __restrict__ k8) {
    __shared__ unsigned tile[56 * 17];   // [x][16 ch-dwords + 1 pad]
    const int n = blockIdx.x / H_;
    const int y = blockIdx.x % H_;
    const float T = fminf(fmaxf(__uint_as_float(*maxbits), 1e-10f), 255.0f);
    const double dinv = 1.0 / (double)T;            // correctly-rounded f64 reciprocal
    const int t = threadIdx.x;
    if (t < 224) {
        const int cb = t / 14, xb = t % 14;         // c0 = 4cb (coalesced within group), x0 = 4xb
        const float* src = x + ((size_t)(n * 64 + 4 * cb)) * HW_ + y * 56 + 4 * xb;
        int kq[4][4];
#pragma unroll
        for (int i = 0; i < 4; i++) {
            float4 v = *(const float4*)(src + (size_t)i * HW_);
            const float e[4] = {v.x, v.y, v.z, v.w};
#pragma unroll
            for (int j = 0; j < 4; j++) {
                const float tc = fminf(fmaxf(e[j], -T), T);
                const float u  = (float)((double)tc * dinv);     // == __fdiv_rn(tc, T)
                kq[i][j] = (int)rintf(__fmul_rn(u, 7.0f));
            }
        }
#pragma unroll
        for (int j = 0; j < 4; j++) {
            const unsigned d = (kq[0][j] & 255) | ((kq[1][j] & 255) << 8) |
                               ((kq[2][j] & 255) << 16) | ((unsigned)(kq[3][j] & 255) << 24);
            tile[(4 * xb + j) * 17 + cb] = d;
        }
    }
    __syncthreads();
    unsigned* dst = (unsigned*)(k8 + ((size_t)(n * 56 + y)) * 56 * 64);
    for (int u = t; u < 896; u += 256)
        dst[u] = tile[(u >> 4) * 17 + (u & 15)];
}

// ------------------------------------------------ fused conv + BN + residual
// grid: B*28 blocks; block = (n, rows y0,y0+1) -> M = 112 positions, N = 64 co.
// LDS layouts are CHUNK-MAJOR: the 16-B MFMA fragment index (q = khalf + 2*kb,
// i.e. ci-window q*16..q*16+15) is the outermost dim, so every ds_read_b128 has
// a 16-B lane stride -> 4-dword bank stride -> conflict-free (8 lanes tile all
// 32 banks). Same bytes as before, just permuted.
template <int LAYER>
__global__ __launch_bounds__(256, 3) void k_conv(const int8_t* __restrict__ kin,
                                                 const int8_t* __restrict__ wb,
                                                 const float* __restrict__ par,
                                                 int8_t* __restrict__ kout,
                                                 float* __restrict__ fout) {
    __shared__ __align__(16) int8_t halo[4 * 4 * 58 * 16];   // [q][row][x][16ci] = 14848 B
    __shared__ __align__(16) int8_t wsm[4 * 9 * 64 * 16];    // [q][tap][co][16ci] = 36864 B
    const int n  = blockIdx.x / 28;
    const int y0 = (blockIdx.x % 28) * 2;
    const int tid = threadIdx.x;

    // stage halo (zero-padded): u = ((r*58+xp)*4 + q) -> 4 consecutive lanes read
    // one full 64-B pixel (perfect coalescing); LDS dest is chunk-major.
    for (int u = tid; u < 928; u += 256) {
        const int q = u & 3, v = u >> 2;
        const int r = v / 58, xp = v % 58;
        const int y = y0 - 1 + r, xg = xp - 1;
        int4 val = {0, 0, 0, 0};
        if (y >= 0 && y < 56 && xg >= 0 && xg < 56)
            val = *(const int4*)(kin + (((size_t)(n * 56 + y)) * 56 + xg) * 64 + q * 16);
        *(int4*)(halo + (((q * 4 + r) * 58 + xp) << 4)) = val;
    }
    // stage this layer's binary weights (global already in LDS order: linear copy)
    const int8_t* wsrc = wb + (size_t)(LAYER - 1) * (4 * 9 * 64 * 16);
    for (int u = tid; u < 2304; u += 256)
        *(int4*)(wsm + u * 16) = *(const int4*)(wsrc + u * 16);
    __syncthreads();

    const int wv = tid >> 6, lane = tid & 63;
    const int mbase = wv * 32;
    const int ml = lane & 31;
    const int khalf = lane >> 5;
    const int m = mbase + ml;
    const int m_eff = (m < 112) ? m : 111;
    const int rm = m_eff / 56, cm = m_eff % 56;

    v16i acc0, acc1;
#pragma unroll
    for (int i = 0; i < 16; i++) { acc0[i] = 0; acc1[i] = 0; }

#pragma unroll
    for (int s = 0; s < 9; s++) {
        const int ky = s / 3, kx = s % 3;
#pragma unroll
        for (int kb = 0; kb < 2; kb++) {
            const int q = khalf + 2 * kb;
            v4i a  = *(const v4i*)(halo + ((((q * 4 + rm + ky) * 58) + cm + kx) << 4));
            v4i b0 = *(const v4i*)(wsm  + (((q * 9 + s) * 64 + ml) << 4));
            v4i b1 = *(const v4i*)(wsm  + (((q * 9 + s) * 64 + 32 + ml) << 4));
            acc0 = __builtin_amdgcn_mfma_i32_32x32x32_i8(a, b0, acc0, 0, 0, 0);
            acc1 = __builtin_amdgcn_mfma_i32_32x32x32_i8(a, b1, acc1, 0, 0, 0);
        }
    }

    // Epilogue, faithful f32 chain; all __fdiv_rn replaced by bit-identical
    // f64 reciprocal-multiplies. Outputs stored DIRECTLY to global (each 64-B
    // line is completed within one wave -> L2 assembles full lines).
    const float* qw = par + (LAYER - 1) * 64;
    const float* qb = par + 128 + (LAYER - 1) * 64;
    const float* sc = par + 256 + (LAYER - 1) * 64;
#pragma unroll
    for (int t = 0; t < 2; t++) {
        const int co = ml + t * 32;
        const float qwf = qw[co], qbf = qb[co], scf = sc[co];
        const int qc = co >> 4, cl = co & 15;
#pragma unroll
        for (int g = 0; g < 4; g++) {
            const int mb = mbase + 8 * g + 4 * khalf;     // 4 consecutive mrows mb..mb+3
            if (mb >= 112) continue;                      // only wv==3, g>=2 (whole group OOB)
            // mb % 4 == 0 and 56 % 4 == 0 -> the 4-row group never straddles y rows
            const int rloc = (mb >= 56) ? 1 : 0;
            const int cl0  = mb - 56 * rloc;
            const int hb   = (((qc * 4 + rloc + 1) * 58) + cl0 + 1) * 16 + cl;
            float vals[4];
#pragma unroll
            for (int i = 0; i < 4; i++) {
                const int   S  = t ? acc1[4 * g + i] : acc0[4 * g + i];   // |S| <= 4032: exact
                const float Sf = (float)S;
                const float convf = __fmul_rn(Sf, scf);                   // = S * 2^p / 7
                const float xb = (float)((double)convf * (1.0 / 576.0));  // == __fdiv_rn(convf,576)
                const float rr = rintf(__fmul_rn(xb, 1023.0f));
                const float q1 = (float)((double)rr * (1.0 / 1023.0));    // == __fdiv_rn(rr,1023)
                const float y1 = __fadd_rn(xb, __fsub_rn(q1, xb));
                const float aq = __fmul_rn(y1, 576.0f);
                const int   kc = (int)halo[hb + 16 * i];                  // residual xq (int8)
                const float xqv = (float)((double)kc * (1.0 / 7.0));      // == __fdiv_rn(kc,7)
                float val = __fadd_rn(__fadd_rn(__fmul_rn(aq, qwf), qbf), xqv);
                val = fminf(fmaxf(val, -1.0f), 1.0f);                     // hardtanh
                if (LAYER == 1) {
                    // T1 == 1.0 (saturation certain): k2 = rint(out * 7)
                    const int k2 = (int)rintf(__fmul_rn(val, 7.0f));
                    kout[(((size_t)(n * 56 + y0 + rloc)) * 56 + cl0 + i) * 64 + co] = (int8_t)k2;
                } else {
                    vals[i] = val;
                }
            }
            if (LAYER == 2) {
                float4 o = make_float4(vals[0], vals[1], vals[2], vals[3]);
                *(float4*)(fout + ((size_t)(n * 64 + co)) * HW_ + y0 * 56 + mb) = o;
            }
        }
    }
}

// ----------------------------------------------------------------- launcher
extern "C" void kernel_launch(void* const* d_in, const int* in_sizes, int n_in,
                              void* d_out, int out_size, void* d_ws, size_t ws_size,
                              hipStream_t stream) {
    const float* x  = (const float*)d_in[0];
    const float* w1 = (const float*)d_in[1];
    const float* w2 = (const float*)d_in[2];
    const float* g1 = (const float*)d_in[3];
    const float* b1 = (const float*)d_in[4];
    const float* m1 = (const float*)d_in[5];
    const float* v1 = (const float*)d_in[6];
    const float* g2 = (const float*)d_in[7];
    const float* b2 = (const float*)d_in[8];
    const float* m2 = (const float*)d_in[9];
    const float* v2 = (const float*)d_in[10];

    char* ws = (char*)d_ws;
    int8_t*  k0  = (int8_t*)(ws + OFF_K0);
    int8_t*  k1  = (int8_t*)(ws + OFF_K1);
    int8_t*  wbp = (int8_t*)(ws + OFF_WB);
    float*   par = (float*)(ws + OFF_PAR);
    unsigned* mx = (unsigned*)(ws + OFF_MAX);

    hipMemsetAsync(mx, 0, 4, stream);
    k_pre<<<1057, 256, 0, stream>>>(x, mx, w1, w2, wbp, par,
                                    g1, b1, m1, v1, g2, b2, m2, v2);
    k_quant<<<B_ * H_, 256, 0, stream>>>(x, mx, k0);
    k_conv<1><<<B_ * 28, 256, 0, stream>>>(k0, wbp, par, k1, nullptr);
    k_conv<2><<<B_ * 28, 256, 0, stream>>>(k1, wbp, par, nullptr, (float*)d_out);
}

// Round 2
// 315.673 us; speedup vs baseline: 1.1126x; 1.0192x over previous
//
#include <hip/hip_runtime.h>
#include <stdint.h>

typedef int v4i   __attribute__((ext_vector_type(4)));
typedef int v16i  __attribute__((ext_vector_type(16)));

#define B_    128
#define C_    64
#define H_    56
#define W_    56
#define HW_   3136
#define NELEM (B_*C_*HW_)          // 25,690,112

// workspace layout (bytes)
#define OFF_K0   0                                  // int8 [B][H][W][C] quantized x (NHWC)
#define OFF_K1   ((size_t)NELEM)                    // int8 x1 (NHWC)
#define OFF_WB   ((size_t)2*NELEM)                  // int8 [2][4][9][64][16] (layer, ci-chunk, tap, co, ci-low) signs
#define OFF_PAR  (OFF_WB + 2*4*9*64*16)             // float: [0..127] qw, [128..255] qb, [256..383] scale=2^p/7
#define OFF_MAX  (OFF_PAR + 384*4)                  // uint32 absmax bits

// --------------------------- numpy-pairwise-faithful wave reduction (576-elem)
__device__ __forceinline__ float pw_reduce64(float r) {
    r = __fadd_rn(r, __shfl_xor(r, 1, 64));
    r = __fadd_rn(r, __shfl_xor(r, 2, 64));
    r = __fadd_rn(r, __shfl_xor(r, 4, 64));
    r = __fadd_rn(r, __shfl_xor(r, 8, 64));
    r = __fadd_rn(r, __shfl_xor(r, 16, 64));
    r = __fadd_rn(r, __shfl_xor(r, 32, 64));
    return r;
}

// ---------------------------------------------------------------- fused prep
// blocks 0..1023   : absmax(x) -> maxbits (one atomic per block)
// blocks 1024..1055: weight binarization, 4 waves/block, wave = (layer, co)
// block  1056      : BN folded affine (threads 0..127)
__global__ void k_pre(const float* __restrict__ x, unsigned* __restrict__ maxbits,
                      const float* __restrict__ w1, const float* __restrict__ w2,
                      int8_t* __restrict__ wb, float* __restrict__ par,
                      const float* __restrict__ g1, const float* __restrict__ bb1,
                      const float* __restrict__ mm1, const float* __restrict__ vv1,
                      const float* __restrict__ g2, const float* __restrict__ bb2,
                      const float* __restrict__ mm2, const float* __restrict__ vv2) {
    __shared__ float smax[4];
    const int b = blockIdx.x;
    const int tid = threadIdx.x;
    if (b < 1024) {
        float m = 0.f;
        const int n4 = NELEM / 4;
        for (int i = b * 256 + tid; i < n4; i += 1024 * 256) {
            float4 v = ((const float4*)x)[i];
            m = fmaxf(m, fmaxf(fmaxf(fabsf(v.x), fabsf(v.y)), fmaxf(fabsf(v.z), fabsf(v.w))));
        }
        for (int off = 32; off; off >>= 1) m = fmaxf(m, __shfl_down(m, off, 64));
        if ((tid & 63) == 0) smax[tid >> 6] = m;
        __syncthreads();
        if (tid == 0) {
            float mm = fmaxf(fmaxf(smax[0], smax[1]), fmaxf(smax[2], smax[3]));
            atomicMax(maxbits, __float_as_uint(mm));   // nonneg floats: uint order == float order
        }
    } else if (b < 1056) {
        const int idx = (b - 1024) * 4 + (tid >> 6);
        const int layer = idx >> 6, co = idx & 63;
        const int lane = tid & 63;
        const float* w = (layer ? w2 : w1) + (size_t)co * 576;
        const int base = (lane >> 3) * 72 + (lane & 7);

        float v[9];
#pragma unroll
        for (int i = 0; i < 9; i++) v[i] = w[base + 8 * i];

        float s = v[0];
#pragma unroll
        for (int i = 1; i < 9; i++) s = __fadd_rn(s, v[i]);
        const float mean = __fdiv_rn(pw_reduce64(s), 576.0f);

        float d0 = __fsub_rn(v[0], mean);
        float sq = __fmul_rn(d0, d0);
#pragma unroll
        for (int i = 1; i < 9; i++) {
            float d = __fsub_rn(v[i], mean);
            sq = __fadd_rn(sq, __fmul_rn(d, d));
        }
        const float sig = __fsqrt_rn(__fdiv_rn(pw_reduce64(sq), 575.0f));

        float sa = fabsf(__fdiv_rn(__fsub_rn(v[0], mean), sig));
#pragma unroll
        for (int i = 1; i < 9; i++)
            sa = __fadd_rn(sa, fabsf(__fdiv_rn(__fsub_rn(v[i], mean), sig)));
        const float ma = __fdiv_rn(pw_reduce64(sa), 576.0f);
        const float p  = rintf(log2f(ma));
        if (lane == 0) par[256 + layer * 64 + co] = __fdiv_rn(exp2f(p), 7.0f);

        // signs -> wb[layer][ci>>4][tap][co][ci&15]  (conv-LDS order, staged linearly)
#pragma unroll
        for (int i = 0; i < 9; i++) {
            int ig = base + 8 * i;
            float d = __fsub_rn(v[i], mean);
            int8_t sg = (d > 0.0f) ? (int8_t)1 : ((d < 0.0f) ? (int8_t)-1 : (int8_t)0);
            int ci = ig / 9, tp = ig % 9;
            wb[((((size_t)layer * 4 + (ci >> 4)) * 9 + tp) * 64 + co) * 16 + (ci & 15)] = sg;
        }
    } else {
        if (tid < 128) {
            const int layer = tid >> 6;
            const int c = tid & 63;
            const float* g  = layer ? g2  : g1;
            const float* be = layer ? bb2 : bb1;
            const float* mu = layer ? mm2 : mm1;
            const float* va = layer ? vv2 : vv1;
            const float stdv = __fsqrt_rn(__fadd_rn(va[c], 1e-5f));
            const float w = __fdiv_rn(g[c], stdv);
            const float bb = __fsub_rn(be[c], __fmul_rn(w, mu[c]));
            float aw = fabsf(w), ab = fabsf(bb);
            for (int off = 32; off; off >>= 1) {
                aw = fmaxf(aw, __shfl_xor(aw, off, 64));
                ab = fmaxf(ab, __shfl_xor(ab, off, 64));
            }
            const float Tw = fminf(fmaxf(aw, 1e-10f), 255.0f);
            const float Tb = fminf(fmaxf(ab, 1e-10f), 255.0f);
            {   // quantize(w, 3): n = 7
                float vq = __fdiv_rn(fminf(fmaxf(w, -Tw), Tw), Tw);
                float r  = rintf(__fmul_rn(vq, 7.0f));
                float qf = __fadd_rn(vq, __fsub_rn(__fdiv_rn(r, 7.0f), vq));
                par[layer * 64 + c] = __fmul_rn(qf, Tw);
            }
            {   // quantize(b, 12): n = 4095
                float vq = __fdiv_rn(fminf(fmaxf(bb, -Tb), Tb), Tb);
                float r  = rintf(__fmul_rn(vq, 4095.0f));
                float qf = __fadd_rn(vq, __fsub_rn(__fdiv_rn(r, 4095.0f), vq));
                par[128 + layer * 64 + c] = __fmul_rn(qf, Tb);
            }
        }
    }
}

// ------------------------------------- quantize x -> int8 k in NHWC layout
// thread = (4-channel block, 4-x block); packs 4 channels per dword -> no byte
// LDS ops. Division by runtime T via correctly-rounded f64 reciprocal multiply
// (bit-identical to __fdiv_rn: f32 quotient is >= 2^-48 rel. from any rounding
// boundary, f64 path error <= 1.5*2^-52).
__global__ void k_quant(const float* __restrict__ x, const unsigned* __restrict__ maxbits,
                        int8_t* __restrict__ k8) {
    __shared__ unsigned tile[56 * 17];   // [x][16 ch-dwords + 1 pad]
    const int n = blockIdx.x / H_;
    const int y = blockIdx.x % H_;
    const float T = fminf(fmaxf(__uint_as_float(*maxbits), 1e-10f), 255.0f);
    const double dinv = 1.0 / (double)T;            // correctly-rounded f64 reciprocal
    const int t = threadIdx.x;
    if (t < 224) {
        const int cb = t / 14, xb = t % 14;         // c0 = 4cb (coalesced within group), x0 = 4xb
        const float* src = x + ((size_t)(n * 64 + 4 * cb)) * HW_ + y * 56 + 4 * xb;
        int kq[4][4];
#pragma unroll
        for (int i = 0; i < 4; i++) {
            float4 v = *(const float4*)(src + (size_t)i * HW_);
            const float e[4] = {v.x, v.y, v.z, v.w};
#pragma unroll
            for (int j = 0; j < 4; j++) {
                const float tc = fminf(fmaxf(e[j], -T), T);
                const float u  = (float)((double)tc * dinv);     // == __fdiv_rn(tc, T)
                kq[i][j] = (int)rintf(__fmul_rn(u, 7.0f));
            }
        }
#pragma unroll
        for (int j = 0; j < 4; j++) {
            const unsigned d = (kq[0][j] & 255) | ((kq[1][j] & 255) << 8) |
                               ((kq[2][j] & 255) << 16) | ((unsigned)(kq[3][j] & 255) << 24);
            tile[(4 * xb + j) * 17 + cb] = d;
        }
    }
    __syncthreads();
    unsigned* dst = (unsigned*)(k8 + ((size_t)(n * 56 + y)) * 56 * 64);
    for (int u = t; u < 896; u += 256)
        dst[u] = tile[(u >> 4) * 17 + (u & 15)];
}

// ------------------------------------------------ fused conv + BN + residual
// grid: B*14 blocks; block = (n, rows y0..y0+3) -> M = 224 positions = 7 waves
// x 32 rows (ZERO M-padding waste), N = 64 co. 448 threads, LDS 59.1 KB ->
// 2 blocks/CU, 14 waves/CU. Chunk-major LDS (q = 16-ci window outermost):
// every ds_read_b128 has 16-B lane stride -> conflict-free.
template <int LAYER>
__global__ __launch_bounds__(448, 2) void k_conv(const int8_t* __restrict__ kin,
                                                 const int8_t* __restrict__ wb,
                                                 const float* __restrict__ par,
                                                 int8_t* __restrict__ kout,
                                                 float* __restrict__ fout) {
    __shared__ __align__(16) int8_t halo[4 * 6 * 58 * 16];   // [q][row][x][16ci] = 22272 B
    __shared__ __align__(16) int8_t wsm[4 * 9 * 64 * 16];    // [q][tap][co][16ci] = 36864 B
    const int n  = blockIdx.x / 14;
    const int y0 = (blockIdx.x % 14) * 4;
    const int tid = threadIdx.x;

    // stage halo (zero-padded): u = (v*4 + q), v = (r*58+xp) -> 4 consecutive
    // lanes read one full 64-B pixel (perfect global coalescing).
    for (int u = tid; u < 1392; u += 448) {
        const int q = u & 3, v = u >> 2;
        const int r = v / 58, xp = v % 58;
        const int y = y0 - 1 + r, xg = xp - 1;
        int4 val = {0, 0, 0, 0};
        if (y >= 0 && y < 56 && xg >= 0 && xg < 56)
            val = *(const int4*)(kin + (((size_t)(n * 56 + y)) * 56 + xg) * 64 + q * 16);
        *(int4*)(halo + (((q * 6 + r) * 58 + xp) << 4)) = val;
    }
    // stage this layer's binary weights (global already in LDS order: linear copy)
    const int8_t* wsrc = wb + (size_t)(LAYER - 1) * (4 * 9 * 64 * 16);
    for (int u = tid; u < 2304; u += 448)
        *(int4*)(wsm + u * 16) = *(const int4*)(wsrc + u * 16);
    __syncthreads();

    const int wv = tid >> 6, lane = tid & 63;
    const int mbase = wv * 32;                 // 0..192, all 224 rows valid
    const int ml = lane & 31;
    const int khalf = lane >> 5;
    const int m = mbase + ml;
    const int rm = m / 56, cm = m % 56;

    v16i acc0, acc1;
#pragma unroll
    for (int i = 0; i < 16; i++) { acc0[i] = 0; acc1[i] = 0; }

#pragma unroll
    for (int s = 0; s < 9; s++) {
        const int ky = s / 3, kx = s % 3;
#pragma unroll
        for (int kb = 0; kb < 2; kb++) {
            const int q = khalf + 2 * kb;
            v4i a  = *(const v4i*)(halo + ((((q * 6 + rm + ky) * 58) + cm + kx) << 4));
            v4i b0 = *(const v4i*)(wsm  + (((q * 9 + s) * 64 + ml) << 4));
            v4i b1 = *(const v4i*)(wsm  + (((q * 9 + s) * 64 + 32 + ml) << 4));
            acc0 = __builtin_amdgcn_mfma_i32_32x32x32_i8(a, b0, acc0, 0, 0, 0);
            acc1 = __builtin_amdgcn_mfma_i32_32x32x32_i8(a, b1, acc1, 0, 0, 0);
        }
    }

    // Epilogue, faithful f32 chain; fixed-constant divides via bit-identical
    // f64 reciprocal-multiplies. Residual read as dword + byte-extract
    // (4-lane same-address broadcast on 4 distinct banks: conflict-free).
    const float* qw = par + (LAYER - 1) * 64;
    const float* qb = par + 128 + (LAYER - 1) * 64;
    const float* sc = par + 256 + (LAYER - 1) * 64;
#pragma unroll
    for (int g = 0; g < 4; g++) {
        const int mb = mbase + 8 * g + 4 * khalf;     // 0..220, 4 consecutive mrows
        // mb % 4 == 0 and 56 % 4 == 0 -> the 4-row group never straddles y rows
        const int rloc = mb / 56;
        const int cl0  = mb % 56;
#pragma unroll
        for (int t = 0; t < 2; t++) {
            const int co = ml + t * 32;
            const float qwf = qw[co], qbf = qb[co], scf = sc[co];
            const int qc = co >> 4, cl = co & 15;
            const int clw = cl & ~3, cb8 = (cl & 3) * 8;
            const int pixbase = (qc * 6 + rloc + 1) * 58 + cl0 + 1;
            float vals[4];
#pragma unroll
            for (int i = 0; i < 4; i++) {
                const int   S  = t ? acc1[4 * g + i] : acc0[4 * g + i];   // |S| <= 4032: exact
                const float Sf = (float)S;
                const float convf = __fmul_rn(Sf, scf);                   // = S * 2^p / 7
                const float xb = (float)((double)convf * (1.0 / 576.0));  // == __fdiv_rn(convf,576)
                const float rr = rintf(__fmul_rn(xb, 1023.0f));
                const float q1 = (float)((double)rr * (1.0 / 1023.0));    // == __fdiv_rn(rr,1023)
                const float y1 = __fadd_rn(xb, __fsub_rn(q1, xb));
                const float aq = __fmul_rn(y1, 576.0f);
                const unsigned wd = *(const unsigned*)(halo + ((pixbase + i) << 4) + clw);
                const int   kc = (int)(int8_t)(wd >> cb8);                // residual xq (int8)
                const float xqv = (float)((double)kc * (1.0 / 7.0));      // == __fdiv_rn(kc,7)
                float val = __fadd_rn(__fadd_rn(__fmul_rn(aq, qwf), qbf), xqv);
                val = fminf(fmaxf(val, -1.0f), 1.0f);                     // hardtanh
                if (LAYER == 1) {
                    // T1 == 1.0 (saturation certain): k2 = rint(out * 7)
                    const int k2 = (int)rintf(__fmul_rn(val, 7.0f));
                    kout[(((size_t)(n * 56 + y0 + rloc)) * 56 + cl0 + i) * 64 + co] = (int8_t)k2;
                } else {
                    vals[i] = val;
                }
            }
            if (LAYER == 2) {
                float4 o = make_float4(vals[0], vals[1], vals[2], vals[3]);
                *(float4*)(fout + ((size_t)(n * 64 + co)) * HW_ + (y0 + rloc) * 56 + cl0) = o;
            }
        }
    }
}

// ----------------------------------------------------------------- launcher
extern "C" void kernel_launch(void* const* d_in, const int* in_sizes, int n_in,
                              void* d_out, int out_size, void* d_ws, size_t ws_size,
                              hipStream_t stream) {
    const float* x  = (const float*)d_in[0];
    const float* w1 = (const float*)d_in[1];
    const float* w2 = (const float*)d_in[2];
    const float* g1 = (const float*)d_in[3];
    const float* b1 = (const float*)d_in[4];
    const float* m1 = (const float*)d_in[5];
    const float* v1 = (const float*)d_in[6];
    const float* g2 = (const float*)d_in[7];
    const float* b2 = (const float*)d_in[8];
    const float* m2 = (const float*)d_in[9];
    const float* v2 = (const float*)d_in[10];

    char* ws = (char*)d_ws;
    int8_t*  k0  = (int8_t*)(ws + OFF_K0);
    int8_t*  k1  = (int8_t*)(ws + OFF_K1);
    int8_t*  wbp = (int8_t*)(ws + OFF_WB);
    float*   par = (float*)(ws + OFF_PAR);
    unsigned* mx = (unsigned*)(ws + OFF_MAX);

    hipMemsetAsync(mx, 0, 4, stream);
    k_pre<<<1057, 256, 0, stream>>>(x, mx, w1, w2, wbp, par,
                                    g1, b1, m1, v1, g2, b2, m2, v2);
    k_quant<<<B_ * H_, 256, 0, stream>>>(x, mx, k0);
    k_conv<1><<<B_ * 14, 448, 0, stream>>>(k0, wbp, par, k1, nullptr);
    k_conv<2><<<B_ * 14, 448, 0, stream>>>(k1, wbp, par, nullptr, (float*)d_out);
}

// Round 3
// 302.341 us; speedup vs baseline: 1.1616x; 1.0441x over previous
//
#include <hip/hip_runtime.h>
#include <stdint.h>

typedef int v4i   __attribute__((ext_vector_type(4)));
typedef int v16i  __attribute__((ext_vector_type(16)));

#define B_    128
#define C_    64
#define H_    56
#define W_    56
#define HW_   3136
#define NELEM (B_*C_*HW_)          // 25,690,112

// workspace layout (bytes)
#define OFF_K0   0                                  // int8 [B][H][W][C] quantized x (NHWC)
#define OFF_K1   ((size_t)NELEM)                    // int8 x1 (NHWC)
#define OFF_WB   ((size_t)2*NELEM)                  // int8 [2][4][9][64][16] (layer, ci-chunk, tap, co, ci-low) signs
#define OFF_PAR  (OFF_WB + 2*4*9*64*16)             // float: [0..127] qw, [128..255] qb, [256..383] scale=2^p/7
#define OFF_MAX  (OFF_PAR + 384*4)                  // uint32 absmax bits

// --------------------------- numpy-pairwise-faithful wave reduction (576-elem)
__device__ __forceinline__ float pw_reduce64(float r) {
    r = __fadd_rn(r, __shfl_xor(r, 1, 64));
    r = __fadd_rn(r, __shfl_xor(r, 2, 64));
    r = __fadd_rn(r, __shfl_xor(r, 4, 64));
    r = __fadd_rn(r, __shfl_xor(r, 8, 64));
    r = __fadd_rn(r, __shfl_xor(r, 16, 64));
    r = __fadd_rn(r, __shfl_xor(r, 32, 64));
    return r;
}

// ---------------------------------------------------------------- fused prep
// blocks 0..1023   : absmax(x) -> maxbits (one atomic per block)
// blocks 1024..1055: weight binarization, 4 waves/block, wave = (layer, co)
// block  1056      : BN folded affine (threads 0..127)
__global__ void k_pre(const float* __restrict__ x, unsigned* __restrict__ maxbits,
                      const float* __restrict__ w1, const float* __restrict__ w2,
                      int8_t* __restrict__ wb, float* __restrict__ par,
                      const float* __restrict__ g1, const float* __restrict__ bb1,
                      const float* __restrict__ mm1, const float* __restrict__ vv1,
                      const float* __restrict__ g2, const float* __restrict__ bb2,
                      const float* __restrict__ mm2, const float* __restrict__ vv2) {
    __shared__ float smax[4];
    const int b = blockIdx.x;
    const int tid = threadIdx.x;
    if (b < 1024) {
        float m = 0.f;
        const int n4 = NELEM / 4;
        for (int i = b * 256 + tid; i < n4; i += 1024 * 256) {
            float4 v = ((const float4*)x)[i];
            m = fmaxf(m, fmaxf(fmaxf(fabsf(v.x), fabsf(v.y)), fmaxf(fabsf(v.z), fabsf(v.w))));
        }
        for (int off = 32; off; off >>= 1) m = fmaxf(m, __shfl_down(m, off, 64));
        if ((tid & 63) == 0) smax[tid >> 6] = m;
        __syncthreads();
        if (tid == 0) {
            float mm = fmaxf(fmaxf(smax[0], smax[1]), fmaxf(smax[2], smax[3]));
            atomicMax(maxbits, __float_as_uint(mm));   // nonneg floats: uint order == float order
        }
    } else if (b < 1056) {
        const int idx = (b - 1024) * 4 + (tid >> 6);
        const int layer = idx >> 6, co = idx & 63;
        const int lane = tid & 63;
        const float* w = (layer ? w2 : w1) + (size_t)co * 576;
        const int base = (lane >> 3) * 72 + (lane & 7);

        float v[9];
#pragma unroll
        for (int i = 0; i < 9; i++) v[i] = w[base + 8 * i];

        float s = v[0];
#pragma unroll
        for (int i = 1; i < 9; i++) s = __fadd_rn(s, v[i]);
        const float mean = __fdiv_rn(pw_reduce64(s), 576.0f);

        float d0 = __fsub_rn(v[0], mean);
        float sq = __fmul_rn(d0, d0);
#pragma unroll
        for (int i = 1; i < 9; i++) {
            float d = __fsub_rn(v[i], mean);
            sq = __fadd_rn(sq, __fmul_rn(d, d));
        }
        const float sig = __fsqrt_rn(__fdiv_rn(pw_reduce64(sq), 575.0f));

        float sa = fabsf(__fdiv_rn(__fsub_rn(v[0], mean), sig));
#pragma unroll
        for (int i = 1; i < 9; i++)
            sa = __fadd_rn(sa, fabsf(__fdiv_rn(__fsub_rn(v[i], mean), sig)));
        const float ma = __fdiv_rn(pw_reduce64(sa), 576.0f);
        const float p  = rintf(log2f(ma));
        if (lane == 0) par[256 + layer * 64 + co] = __fdiv_rn(exp2f(p), 7.0f);

        // signs -> wb[layer][ci>>4][tap][co][ci&15]  (conv-LDS order, staged linearly)
#pragma unroll
        for (int i = 0; i < 9; i++) {
            int ig = base + 8 * i;
            float d = __fsub_rn(v[i], mean);
            int8_t sg = (d > 0.0f) ? (int8_t)1 : ((d < 0.0f) ? (int8_t)-1 : (int8_t)0);
            int ci = ig / 9, tp = ig % 9;
            wb[((((size_t)layer * 4 + (ci >> 4)) * 9 + tp) * 64 + co) * 16 + (ci & 15)] = sg;
        }
    } else {
        if (tid < 128) {
            const int layer = tid >> 6;
            const int c = tid & 63;
            const float* g  = layer ? g2  : g1;
            const float* be = layer ? bb2 : bb1;
            const float* mu = layer ? mm2 : mm1;
            const float* va = layer ? vv2 : vv1;
            const float stdv = __fsqrt_rn(__fadd_rn(va[c], 1e-5f));
            const float w = __fdiv_rn(g[c], stdv);
            const float bb = __fsub_rn(be[c], __fmul_rn(w, mu[c]));
            float aw = fabsf(w), ab = fabsf(bb);
            for (int off = 32; off; off >>= 1) {
                aw = fmaxf(aw, __shfl_xor(aw, off, 64));
                ab = fmaxf(ab, __shfl_xor(ab, off, 64));
            }
            const float Tw = fminf(fmaxf(aw, 1e-10f), 255.0f);
            const float Tb = fminf(fmaxf(ab, 1e-10f), 255.0f);
            {   // quantize(w, 3): n = 7
                float vq = __fdiv_rn(fminf(fmaxf(w, -Tw), Tw), Tw);
                float r  = rintf(__fmul_rn(vq, 7.0f));
                float qf = __fadd_rn(vq, __fsub_rn(__fdiv_rn(r, 7.0f), vq));
                par[layer * 64 + c] = __fmul_rn(qf, Tw);
            }
            {   // quantize(b, 12): n = 4095
                float vq = __fdiv_rn(fminf(fmaxf(bb, -Tb), Tb), Tb);
                float r  = rintf(__fmul_rn(vq, 4095.0f));
                float qf = __fadd_rn(vq, __fsub_rn(__fdiv_rn(r, 4095.0f), vq));
                par[128 + layer * 64 + c] = __fmul_rn(qf, Tb);
            }
        }
    }
}

// ------------------------------------- quantize x -> int8 k in NHWC layout
// thread = (4-channel block, 4-x block); packs 4 channels per dword -> no byte
// LDS ops. Division by runtime T via correctly-rounded f64 reciprocal multiply
// (bit-identical to __fdiv_rn).
__global__ void k_quant(const float* __restrict__ x, const unsigned* __restrict__ maxbits,
                        int8_t* __restrict__ k8) {
    __shared__ unsigned tile[56 * 17];   // [x][16 ch-dwords + 1 pad]
    const int n = blockIdx.x / H_;
    const int y = blockIdx.x % H_;
    const float T = fminf(fmaxf(__uint_as_float(*maxbits), 1e-10f), 255.0f);
    const double dinv = 1.0 / (double)T;            // correctly-rounded f64 reciprocal
    const int t = threadIdx.x;
    if (t < 224) {
        const int cb = t / 14, xb = t % 14;         // c0 = 4cb (coalesced within group), x0 = 4xb
        const float* src = x + ((size_t)(n * 64 + 4 * cb)) * HW_ + y * 56 + 4 * xb;
        int kq[4][4];
#pragma unroll
        for (int i = 0; i < 4; i++) {
            float4 v = *(const float4*)(src + (size_t)i * HW_);
            const float e[4] = {v.x, v.y, v.z, v.w};
#pragma unroll
            for (int j = 0; j < 4; j++) {
                const float tc = fminf(fmaxf(e[j], -T), T);
                const float u  = (float)((double)tc * dinv);     // == __fdiv_rn(tc, T)
                kq[i][j] = (int)rintf(__fmul_rn(u, 7.0f));
            }
        }
#pragma unroll
        for (int j = 0; j < 4; j++) {
            const unsigned d = (kq[0][j] & 255) | ((kq[1][j] & 255) << 8) |
                               ((kq[2][j] & 255) << 16) | ((unsigned)(kq[3][j] & 255) << 24);
            tile[(4 * xb + j) * 17 + cb] = d;
        }
    }
    __syncthreads();
    unsigned* dst = (unsigned*)(k8 + ((size_t)(n * 56 + y)) * 56 * 64);
    for (int u = t; u < 896; u += 256)
        dst[u] = tile[(u >> 4) * 17 + (u & 15)];
}

// ------------------------------------------------ fused conv + BN + residual
// grid: B*7 blocks; block = (n, rows y0..y0+7) -> M = 448 positions = 14 waves
// x 32 rows (zero M-padding), N = 64 co. 896 threads, LDS 74.0 KB ->
// 2 blocks/CU = 28 waves/CU (2x round-2's latency hiding); weight staging and
// barriers per unit work halved; halo y-amplification 1.25x. Chunk-major LDS
// (q = 16-ci window outermost): every ds_read_b128 has 16-B lane stride ->
// conflict-free. __launch_bounds__(896,7) pins VGPR<=73 so 2 blocks stay
// resident (round-0 measured 68 for this inner body).
template <int LAYER>
__global__ __launch_bounds__(896, 7) void k_conv(const int8_t* __restrict__ kin,
                                                 const int8_t* __restrict__ wb,
                                                 const float* __restrict__ par,
                                                 int8_t* __restrict__ kout,
                                                 float* __restrict__ fout) {
    __shared__ __align__(16) int8_t halo[4 * 10 * 58 * 16];  // [q][row][x][16ci] = 37120 B
    __shared__ __align__(16) int8_t wsm[4 * 9 * 64 * 16];    // [q][tap][co][16ci] = 36864 B
    const int n  = blockIdx.x / 7;
    const int y0 = (blockIdx.x % 7) * 8;
    const int tid = threadIdx.x;

    // stage halo (zero-padded): u = (v*4 + q), v = (r*58+xp) -> 4 consecutive
    // lanes read one full 64-B pixel (perfect global coalescing).
    for (int u = tid; u < 2320; u += 896) {
        const int q = u & 3, v = u >> 2;
        const int r = v / 58, xp = v % 58;
        const int y = y0 - 1 + r, xg = xp - 1;
        int4 val = {0, 0, 0, 0};
        if (y >= 0 && y < 56 && xg >= 0 && xg < 56)
            val = *(const int4*)(kin + (((size_t)(n * 56 + y)) * 56 + xg) * 64 + q * 16);
        *(int4*)(halo + (((q * 10 + r) * 58 + xp) << 4)) = val;
    }
    // stage this layer's binary weights (global already in LDS order: linear copy)
    const int8_t* wsrc = wb + (size_t)(LAYER - 1) * (4 * 9 * 64 * 16);
    for (int u = tid; u < 2304; u += 896)
        *(int4*)(wsm + u * 16) = *(const int4*)(wsrc + u * 16);
    __syncthreads();

    const int wv = tid >> 6, lane = tid & 63;
    const int mbase = wv * 32;                 // 0..416, all 448 rows valid
    const int ml = lane & 31;
    const int khalf = lane >> 5;
    const int m = mbase + ml;
    const int rm = m / 56, cm = m % 56;

    v16i acc0, acc1;
#pragma unroll
    for (int i = 0; i < 16; i++) { acc0[i] = 0; acc1[i] = 0; }

#pragma unroll
    for (int s = 0; s < 9; s++) {
        const int ky = s / 3, kx = s % 3;
#pragma unroll
        for (int kb = 0; kb < 2; kb++) {
            const int q = khalf + 2 * kb;
            v4i a  = *(const v4i*)(halo + ((((q * 10 + rm + ky) * 58) + cm + kx) << 4));
            v4i b0 = *(const v4i*)(wsm  + (((q * 9 + s) * 64 + ml) << 4));
            v4i b1 = *(const v4i*)(wsm  + (((q * 9 + s) * 64 + 32 + ml) << 4));
            acc0 = __builtin_amdgcn_mfma_i32_32x32x32_i8(a, b0, acc0, 0, 0, 0);
            acc1 = __builtin_amdgcn_mfma_i32_32x32x32_i8(a, b1, acc1, 0, 0, 0);
        }
    }

    // Epilogue, faithful f32 chain; fixed-constant divides via bit-identical
    // f64 reciprocal-multiplies. Residual read as dword + byte-extract.
    // t outermost: qw/qb/sc loaded once per t (not per g).
    const float* qw = par + (LAYER - 1) * 64;
    const float* qb = par + 128 + (LAYER - 1) * 64;
    const float* sc = par + 256 + (LAYER - 1) * 64;
#pragma unroll
    for (int t = 0; t < 2; t++) {
        const int co = ml + t * 32;
        const float qwf = qw[co], qbf = qb[co], scf = sc[co];
        const int qc = co >> 4, cl = co & 15;
        const int clw = cl & ~3, cb8 = (cl & 3) * 8;
#pragma unroll
        for (int g = 0; g < 4; g++) {
            const int mb = mbase + 8 * g + 4 * khalf;     // 0..444, 4 consecutive mrows
            // mb % 4 == 0 and 56 % 4 == 0 -> the 4-row group never straddles y rows
            const int rloc = mb / 56;
            const int cl0  = mb % 56;
            const int pixbase = (qc * 10 + rloc + 1) * 58 + cl0 + 1;
            float vals[4];
#pragma unroll
            for (int i = 0; i < 4; i++) {
                const int   S  = t ? acc1[4 * g + i] : acc0[4 * g + i];   // |S| <= 4032: exact
                const float Sf = (float)S;
                const float convf = __fmul_rn(Sf, scf);                   // = S * 2^p / 7
                const float xb = (float)((double)convf * (1.0 / 576.0));  // == __fdiv_rn(convf,576)
                const float rr = rintf(__fmul_rn(xb, 1023.0f));
                const float q1 = (float)((double)rr * (1.0 / 1023.0));    // == __fdiv_rn(rr,1023)
                const float y1 = __fadd_rn(xb, __fsub_rn(q1, xb));
                const float aq = __fmul_rn(y1, 576.0f);
                const unsigned wd = *(const unsigned*)(halo + ((pixbase + i) << 4) + clw);
                const int   kc = (int)(int8_t)(wd >> cb8);                // residual xq (int8)
                const float xqv = (float)((double)kc * (1.0 / 7.0));      // == __fdiv_rn(kc,7)
                float val = __fadd_rn(__fadd_rn(__fmul_rn(aq, qwf), qbf), xqv);
                val = fminf(fmaxf(val, -1.0f), 1.0f);                     // hardtanh
                if (LAYER == 1) {
                    // T1 == 1.0 (saturation certain): k2 = rint(out * 7)
                    const int k2 = (int)rintf(__fmul_rn(val, 7.0f));
                    kout[(((size_t)(n * 56 + y0 + rloc)) * 56 + cl0 + i) * 64 + co] = (int8_t)k2;
                } else {
                    vals[i] = val;
                }
            }
            if (LAYER == 2) {
                float4 o = make_float4(vals[0], vals[1], vals[2], vals[3]);
                *(float4*)(fout + ((size_t)(n * 64 + co)) * HW_ + (y0 + rloc) * 56 + cl0) = o;
            }
        }
    }
}

// ----------------------------------------------------------------- launcher
extern "C" void kernel_launch(void* const* d_in, const int* in_sizes, int n_in,
                              void* d_out, int out_size, void* d_ws, size_t ws_size,
                              hipStream_t stream) {
    const float* x  = (const float*)d_in[0];
    const float* w1 = (const float*)d_in[1];
    const float* w2 = (const float*)d_in[2];
    const float* g1 = (const float*)d_in[3];
    const float* b1 = (const float*)d_in[4];
    const float* m1 = (const float*)d_in[5];
    const float* v1 = (const float*)d_in[6];
    const float* g2 = (const float*)d_in[7];
    const float* b2 = (const float*)d_in[8];
    const float* m2 = (const float*)d_in[9];
    const float* v2 = (const float*)d_in[10];

    char* ws = (char*)d_ws;
    int8_t*  k0  = (int8_t*)(ws + OFF_K0);
    int8_t*  k1  = (int8_t*)(ws + OFF_K1);
    int8_t*  wbp = (int8_t*)(ws + OFF_WB);
    float*   par = (float*)(ws + OFF_PAR);
    unsigned* mx = (unsigned*)(ws + OFF_MAX);

    hipMemsetAsync(mx, 0, 4, stream);
    k_pre<<<1057, 256, 0, stream>>>(x, mx, w1, w2, wbp, par,
                                    g1, b1, m1, v1, g2, b2, m2, v2);
    k_quant<<<B_ * H_, 256, 0, stream>>>(x, mx, k0);
    k_conv<1><<<B_ * 7, 896, 0, stream>>>(k0, wbp, par, k1, nullptr);
    k_conv<2><<<B_ * 7, 896, 0, stream>>>(k1, wbp, par, nullptr, (float*)d_out);
}